// Round 1
// baseline (487.796 us; speedup 1.0000x reference)
//
#include <hip/hip_runtime.h>
#include <stdint.h>

typedef unsigned short u16;
typedef __bf16 bf16_t;
typedef bf16_t bf16x8 __attribute__((ext_vector_type(8)));
typedef float f32x4 __attribute__((ext_vector_type(4)));

__device__ __forceinline__ float b2f(u16 u) {
  union { unsigned int i; float f; } v; v.i = ((unsigned int)u) << 16; return v.f;
}
__device__ __forceinline__ u16 f2b(float f) {
  union { float f; unsigned int i; } v; v.f = f;
  unsigned int r = v.i + 0x7fffu + ((v.i >> 16) & 1u);  // RNE
  return (u16)(r >> 16);
}
__device__ __forceinline__ void async16(const void* g, void* lds) {
  __builtin_amdgcn_global_load_lds((const __attribute__((address_space(1))) void*)g,
                                   (__attribute__((address_space(3))) void*)lds,
                                   16, 0, 0);
}

// ---------------- fp32 -> bf16 conversion ----------------
__global__ void k_f2b(const float* __restrict__ src, u16* __restrict__ dst, int n) {
  int i = (blockIdx.x * 256 + threadIdx.x) * 4;
  int stride = gridDim.x * 256 * 4;
  for (; i < n; i += stride) {
    float4 v = *reinterpret_cast<const float4*>(src + i);
    u16 o[4] = { f2b(v.x), f2b(v.y), f2b(v.z), f2b(v.w) };
    *reinterpret_cast<uint2*>(dst + i) = *reinterpret_cast<uint2*>(o);
  }
}

// ---------------- GEMM: C = A(MxK) * B(NxK)^T, bf16 in, f32 or bf16 out ----------------
// 128x128 tile, BK=32, 4 waves (each 64x64), mfma_f32_16x16x32_bf16, global_load_lds staging.
template<int OUT_BF16>
__device__ __forceinline__ void gemm_core(const u16* __restrict__ A, const u16* __restrict__ B,
                                          void* __restrict__ Cv, int M, int N, int K,
                                          int m0, int n0) {
  __shared__ __align__(16) u16 As[128 * 32];
  __shared__ __align__(16) u16 Bs[128 * 32];
  const int tid = threadIdx.x, lane = tid & 63, w = tid >> 6;
  const int wr = (w >> 1) * 64, wc = (w & 1) * 64;
  const int lr = lane & 15, lk = (lane >> 4) * 8;
  f32x4 acc[4][4] = {};
  for (int k0 = 0; k0 < K; k0 += 32) {
    if (k0) __syncthreads();          // protect LDS from overwrite while others still read
#pragma unroll
    for (int it = 0; it < 2; ++it) {
      int c = it * 256 + tid;         // 16B chunk id, 512 chunks per 8KB tile
      int row = c >> 2, kc = (c & 3) * 8;
      async16(A + (size_t)(m0 + row) * K + k0 + kc, (char*)As + c * 16);
      async16(B + (size_t)(n0 + row) * K + k0 + kc, (char*)Bs + c * 16);
    }
    __syncthreads();                  // drains vmcnt(0) then barrier
    bf16x8 af[4], bfr[4];
#pragma unroll
    for (int i = 0; i < 4; ++i)
      af[i] = *reinterpret_cast<const bf16x8*>(&As[(wr + i * 16 + lr) * 32 + lk]);
#pragma unroll
    for (int i = 0; i < 4; ++i)
      bfr[i] = *reinterpret_cast<const bf16x8*>(&Bs[(wc + i * 16 + lr) * 32 + lk]);
#pragma unroll
    for (int i = 0; i < 4; ++i)
#pragma unroll
      for (int j = 0; j < 4; ++j)
        acc[i][j] = __builtin_amdgcn_mfma_f32_16x16x32_bf16(af[i], bfr[j], acc[i][j], 0, 0, 0);
  }
  const int er = (lane >> 4) * 4, ec = lane & 15;
#pragma unroll
  for (int i = 0; i < 4; ++i)
#pragma unroll
    for (int j = 0; j < 4; ++j)
#pragma unroll
      for (int jj = 0; jj < 4; ++jj) {
        int r = m0 + wr + i * 16 + er + jj;
        int cc = n0 + wc + j * 16 + ec;
        if (OUT_BF16) ((u16*)Cv)[(size_t)r * N + cc] = f2b(acc[i][j][jj]);
        else          ((float*)Cv)[(size_t)r * N + cc] = acc[i][j][jj];
      }
}

__global__ __launch_bounds__(256) void k_gemm_bf16(const u16* A, const u16* B, u16* C,
                                                   int M, int N, int K) {
  gemm_core<1>(A, B, C, M, N, K, blockIdx.y * 128, blockIdx.x * 128);
}
__global__ __launch_bounds__(256) void k_gemm_f32(const u16* A, const u16* B, float* C,
                                                  int M, int N, int K) {
  gemm_core<0>(A, B, C, M, N, K, blockIdx.y * 128, blockIdx.x * 128);
}
__global__ __launch_bounds__(256) void k_gemm_kv(const u16* A, const u16* Bk, const u16* Bv,
                                                 u16* Ck, u16* Cvp, int M, int N, int K) {
  const u16* B = blockIdx.z ? Bv : Bk;
  u16* C = blockIdx.z ? Cvp : Ck;
  gemm_core<1>(A, B, C, M, N, K, blockIdx.y * 128, blockIdx.x * 128);
}

// ---------------- RMSNorm(offset) + RoPE, in place. one wave per (token, head) ----------------
__global__ __launch_bounds__(256) void k_normrope(u16* __restrict__ buf,
                                                  const float* __restrict__ cosb,
                                                  const float* __restrict__ sinb,
                                                  const float* __restrict__ w,
                                                  int nheads, int rowstride, int headstride,
                                                  int total) {
  int wid = blockIdx.x * 4 + (threadIdx.x >> 6);
  int lane = threadIdx.x & 63;
  int t = wid / nheads, h = wid - t * nheads;
  if (t >= total) return;
  u16* base = buf + (size_t)t * rowstride + h * headstride;
  float a = b2f(base[lane]), b = b2f(base[lane + 64]);
  float ss = a * a + b * b;
#pragma unroll
  for (int m = 32; m >= 1; m >>= 1) ss += __shfl_xor(ss, m, 64);
  float r = rsqrtf(ss * (1.0f / 128.0f) + 1e-6f);
  float qa = (1.0f + w[lane]) * a * r;
  float qb = (1.0f + w[lane + 64]) * b * r;
  const float* cr = cosb + (size_t)t * 128;
  const float* sr = sinb + (size_t)t * 128;
  float oa = qa * cr[lane] - qb * sr[lane];            // i < 64: rot = -x[i+64]
  float ob = qb * cr[lane + 64] + qa * sr[lane + 64];  // i >= 64: rot = x[i-64]
  base[lane] = f2b(oa);
  base[lane + 64] = f2b(ob);
}

// ---------------- transpose (rows x cols) -> (cols x rows), bf16 ----------------
__global__ __launch_bounds__(256) void k_transpose(const u16* __restrict__ src,
                                                   u16* __restrict__ dst, int rows, int cols) {
  __shared__ u16 tile[32][33];
  int bx = blockIdx.x * 32, by = blockIdx.y * 32;
  int tx = threadIdx.x & 31, ty = threadIdx.x >> 5;  // ty 0..7
#pragma unroll
  for (int i = 0; i < 4; ++i)
    tile[ty + i * 8][tx] = src[(size_t)(bx + ty + i * 8) * cols + by + tx];
  __syncthreads();
#pragma unroll
  for (int i = 0; i < 4; ++i)
    dst[(size_t)(by + ty + i * 8) * rows + bx + tx] = tile[tx][ty + i * 8];
}

// ---------------- flash attention + gate ----------------
// grid(total/64, H). 4 waves/block, each wave owns 16 q-rows. KV tiles of 32.
__global__ __launch_bounds__(256) void k_attn(const u16* __restrict__ qg,  // total x 4096
                                              const u16* __restrict__ kb,  // total x 512
                                              const u16* __restrict__ vt,  // 512 x total
                                              u16* __restrict__ outg,      // total x 2048
                                              const int* __restrict__ cu, int n_seq, int total) {
  __shared__ __align__(16) u16 Ps[4][16][40];  // per-wave P bounce, padded stride
  const int tid = threadIdx.x, lane = tid & 63, w = tid >> 6;
  const int h = blockIdx.y, kh = h >> 2;
  const int qr0 = blockIdx.x * 64 + w * 16;
  int seg_start = 0, seg_end = total;
  for (int s = 0; s < n_seq; ++s) {
    int a = cu[s], b = cu[s + 1];
    if (qr0 >= a && qr0 < b) { seg_start = a; seg_end = b; }
  }
  const int g = lane >> 4, c16 = lane & 15;
  bf16x8 qf[4];
#pragma unroll
  for (int cc = 0; cc < 4; ++cc)
    qf[cc] = *reinterpret_cast<const bf16x8*>(qg + (size_t)(qr0 + c16) * 4096 + h * 256 + cc * 32 + g * 8);
  f32x4 o[8] = {};
  float mrow[4] = { -1e30f, -1e30f, -1e30f, -1e30f };
  float lrow[4] = { 0.f, 0.f, 0.f, 0.f };
  const float scale = 0.08838834764831845f;  // 1/sqrt(128)
  const int kv_end = (seg_end < qr0 + 16) ? seg_end : (qr0 + 16);
  for (int kv0 = seg_start; kv0 < kv_end; kv0 += 32) {
    f32x4 s0 = {}, s1 = {};
#pragma unroll
    for (int cc = 0; cc < 4; ++cc) {
      bf16x8 kf0 = *reinterpret_cast<const bf16x8*>(kb + (size_t)(kv0 + c16) * 512 + kh * 128 + cc * 32 + g * 8);
      bf16x8 kf1 = *reinterpret_cast<const bf16x8*>(kb + (size_t)(kv0 + 16 + c16) * 512 + kh * 128 + cc * 32 + g * 8);
      s0 = __builtin_amdgcn_mfma_f32_16x16x32_bf16(qf[cc], kf0, s0, 0, 0, 0);
      s1 = __builtin_amdgcn_mfma_f32_16x16x32_bf16(qf[cc], kf1, s1, 0, 0, 0);
    }
#pragma unroll
    for (int jj = 0; jj < 4; ++jj) {
      int row = qr0 + g * 4 + jj;
      float a = s0[jj] * scale; if (kv0 + c16 > row) a = -1e30f;
      float b = s1[jj] * scale; if (kv0 + 16 + c16 > row) b = -1e30f;
      float pm = fmaxf(a, b);
#pragma unroll
      for (int mm = 8; mm >= 1; mm >>= 1) pm = fmaxf(pm, __shfl_xor(pm, mm, 16));
      float nm = fmaxf(mrow[jj], pm);
      float fs = __expf(mrow[jj] - nm);
      float pa = __expf(a - nm), pb = __expf(b - nm);
      float psum = pa + pb;
#pragma unroll
      for (int mm = 8; mm >= 1; mm >>= 1) psum += __shfl_xor(psum, mm, 16);
      lrow[jj] = lrow[jj] * fs + psum;
      mrow[jj] = nm;
#pragma unroll
      for (int db = 0; db < 8; ++db) o[db][jj] *= fs;
      Ps[w][g * 4 + jj][c16] = f2b(pa);
      Ps[w][g * 4 + jj][16 + c16] = f2b(pb);
    }
    bf16x8 pf = *reinterpret_cast<const bf16x8*>(&Ps[w][c16][g * 8]);
#pragma unroll
    for (int db = 0; db < 8; ++db) {
      bf16x8 vf = *reinterpret_cast<const bf16x8*>(vt + (size_t)(kh * 128 + db * 16 + c16) * total + kv0 + g * 8);
      o[db] = __builtin_amdgcn_mfma_f32_16x16x32_bf16(pf, vf, o[db], 0, 0, 0);
    }
  }
#pragma unroll
  for (int db = 0; db < 8; ++db)
#pragma unroll
    for (int jj = 0; jj < 4; ++jj) {
      int r = qr0 + g * 4 + jj;
      int d = db * 16 + c16;
      float gate = b2f(qg[(size_t)r * 4096 + h * 256 + 128 + d]);
      float sig = 1.0f / (1.0f + __expf(-gate));
      float val = (o[db][jj] / lrow[jj]) * sig;
      outg[(size_t)r * 2048 + h * 128 + d] = f2b(val);
    }
}

extern "C" void kernel_launch(void* const* d_in, const int* in_sizes, int n_in,
                              void* d_out, int out_size, void* d_ws, size_t ws_size,
                              hipStream_t stream) {
  const float* x    = (const float*)d_in[0];
  const float* cosb = (const float*)d_in[1];
  const float* sinb = (const float*)d_in[2];
  const float* Wq   = (const float*)d_in[3];
  const float* Wk   = (const float*)d_in[4];
  const float* Wv   = (const float*)d_in[5];
  const float* Wo   = (const float*)d_in[6];
  const float* qnw  = (const float*)d_in[7];
  const float* knw  = (const float*)d_in[8];
  const int*   cu   = (const int*)d_in[9];
  const int n_seq = in_sizes[9] - 1;

  const int hidden = 2048, H = 16, KVH = 4, D = 128;
  const int total = in_sizes[0] / hidden;  // 4096
  const int NQ = H * D * 2;                // 4096
  const int NKV = KVH * D;                 // 512

  char* ws = (char*)d_ws;
  size_t off = 0;
  auto alloc = [&](size_t elems) {
    u16* p = (u16*)(ws + off);
    off += elems * 2;
    off = (off + 255) & ~(size_t)255;
    return p;
  };
  u16* xb   = alloc((size_t)total * hidden);
  u16* Wqb  = alloc((size_t)NQ * hidden);
  u16* Wkb  = alloc((size_t)NKV * hidden);
  u16* Wvb  = alloc((size_t)NKV * hidden);
  u16* Wob  = alloc((size_t)hidden * (H * D));
  u16* qgb  = alloc((size_t)total * NQ);
  u16* kbuf = alloc((size_t)total * NKV);
  u16* vbuf = alloc((size_t)total * NKV);
  u16* vtb  = alloc((size_t)total * NKV);
  u16* attg = Wqb;  // alias: Wqb is dead after GEMM1, attg written after

  auto cgrid = [](int n) { int g = (n / 4 + 255) / 256; return g > 2048 ? 2048 : g; };
  k_f2b<<<cgrid(total * hidden), 256, 0, stream>>>(x, xb, total * hidden);
  k_f2b<<<cgrid(NQ * hidden), 256, 0, stream>>>(Wq, Wqb, NQ * hidden);
  k_f2b<<<cgrid(NKV * hidden), 256, 0, stream>>>(Wk, Wkb, NKV * hidden);
  k_f2b<<<cgrid(NKV * hidden), 256, 0, stream>>>(Wv, Wvb, NKV * hidden);
  k_f2b<<<cgrid(hidden * H * D), 256, 0, stream>>>(Wo, Wob, hidden * H * D);

  // qg = x @ Wq^T
  k_gemm_bf16<<<dim3(NQ / 128, total / 128), 256, 0, stream>>>(xb, Wqb, qgb, total, NQ, hidden);
  // k,v = x @ Wk^T, x @ Wv^T
  k_gemm_kv<<<dim3(NKV / 128, total / 128, 2), 256, 0, stream>>>(xb, Wkb, Wvb, kbuf, vbuf,
                                                                 total, NKV, hidden);
  // v^T for attention PV operand
  k_transpose<<<dim3(total / 32, NKV / 32), 256, 0, stream>>>(vbuf, vtb, total, NKV);
  // rmsnorm+rope in place (q lives in qg at head stride 256; k in kbuf at stride 128)
  k_normrope<<<total * H / 4, 256, 0, stream>>>(qgb, cosb, sinb, qnw, H, NQ, 2 * D, total);
  k_normrope<<<total * KVH / 4, 256, 0, stream>>>(kbuf, cosb, sinb, knw, KVH, NKV, D, total);
  // flash attention + sigmoid gate
  k_attn<<<dim3(total / 64, H), 256, 0, stream>>>(qgb, kbuf, vtb, attg, cu, n_seq, total);
  // out = attg @ Wo^T  (f32 to d_out)
  k_gemm_f32<<<dim3(hidden / 128, total / 128), 256, 0, stream>>>(attg, Wob, (float*)d_out,
                                                                  total, hidden, H * D);
}

// Round 2
// 432.295 us; speedup vs baseline: 1.1284x; 1.1284x over previous
//
#include <hip/hip_runtime.h>
#include <stdint.h>

typedef unsigned short u16;
typedef __bf16 bf16_t;
typedef bf16_t bf16x8 __attribute__((ext_vector_type(8)));
typedef float f32x4 __attribute__((ext_vector_type(4)));

__device__ __forceinline__ float b2f(u16 u) {
  union { unsigned int i; float f; } v; v.i = ((unsigned int)u) << 16; return v.f;
}
__device__ __forceinline__ u16 f2b(float f) {
  union { float f; unsigned int i; } v; v.f = f;
  unsigned int r = v.i + 0x7fffu + ((v.i >> 16) & 1u);  // RNE
  return (u16)(r >> 16);
}
__device__ __forceinline__ unsigned int pk2(float a, float b) {
  return (unsigned int)f2b(a) | ((unsigned int)f2b(b) << 16);
}
__device__ __forceinline__ void async16(const void* g, void* lds) {
  __builtin_amdgcn_global_load_lds((const __attribute__((address_space(1))) void*)g,
                                   (__attribute__((address_space(3))) void*)lds,
                                   16, 0, 0);
}

// ---------------- fp32 -> bf16 conversion ----------------
__global__ void k_f2b(const float* __restrict__ src, u16* __restrict__ dst, int n) {
  int i = (blockIdx.x * 256 + threadIdx.x) * 4;
  int stride = gridDim.x * 256 * 4;
  for (; i < n; i += stride) {
    float4 v = *reinterpret_cast<const float4*>(src + i);
    u16 o[4] = { f2b(v.x), f2b(v.y), f2b(v.z), f2b(v.w) };
    *reinterpret_cast<uint2*>(dst + i) = *reinterpret_cast<uint2*>(o);
  }
}

// ---------------- GEMM: C = A(MxK) * B(NxK)^T, bf16 in, f32 or bf16 out ----------------
template<int OUT_BF16>
__device__ __forceinline__ void gemm_core(const u16* __restrict__ A, const u16* __restrict__ B,
                                          void* __restrict__ Cv, int M, int N, int K,
                                          int m0, int n0) {
  __shared__ __align__(16) u16 As[128 * 32];
  __shared__ __align__(16) u16 Bs[128 * 32];
  const int tid = threadIdx.x, lane = tid & 63, w = tid >> 6;
  const int wr = (w >> 1) * 64, wc = (w & 1) * 64;
  const int lr = lane & 15, lk = (lane >> 4) * 8;
  f32x4 acc[4][4] = {};
  for (int k0 = 0; k0 < K; k0 += 32) {
    if (k0) __syncthreads();
#pragma unroll
    for (int it = 0; it < 2; ++it) {
      int c = it * 256 + tid;
      int row = c >> 2, kc = (c & 3) * 8;
      async16(A + (size_t)(m0 + row) * K + k0 + kc, (char*)As + c * 16);
      async16(B + (size_t)(n0 + row) * K + k0 + kc, (char*)Bs + c * 16);
    }
    __syncthreads();
    bf16x8 af[4], bfr[4];
#pragma unroll
    for (int i = 0; i < 4; ++i)
      af[i] = *reinterpret_cast<const bf16x8*>(&As[(wr + i * 16 + lr) * 32 + lk]);
#pragma unroll
    for (int i = 0; i < 4; ++i)
      bfr[i] = *reinterpret_cast<const bf16x8*>(&Bs[(wc + i * 16 + lr) * 32 + lk]);
#pragma unroll
    for (int i = 0; i < 4; ++i)
#pragma unroll
      for (int j = 0; j < 4; ++j)
        acc[i][j] = __builtin_amdgcn_mfma_f32_16x16x32_bf16(af[i], bfr[j], acc[i][j], 0, 0, 0);
  }
  const int er = (lane >> 4) * 4, ec = lane & 15;
#pragma unroll
  for (int i = 0; i < 4; ++i)
#pragma unroll
    for (int j = 0; j < 4; ++j)
#pragma unroll
      for (int jj = 0; jj < 4; ++jj) {
        int r = m0 + wr + i * 16 + er + jj;
        int cc = n0 + wc + j * 16 + ec;
        if (OUT_BF16) ((u16*)Cv)[(size_t)r * N + cc] = f2b(acc[i][j][jj]);
        else          ((float*)Cv)[(size_t)r * N + cc] = acc[i][j][jj];
      }
}

__global__ __launch_bounds__(256) void k_gemm_bf16(const u16* A, const u16* B, u16* C,
                                                   int M, int N, int K) {
  gemm_core<1>(A, B, C, M, N, K, blockIdx.y * 128, blockIdx.x * 128);
}
__global__ __launch_bounds__(256) void k_gemm_f32(const u16* A, const u16* B, float* C,
                                                  int M, int N, int K) {
  gemm_core<0>(A, B, C, M, N, K, blockIdx.y * 128, blockIdx.x * 128);
}
__global__ __launch_bounds__(256) void k_gemm_kv(const u16* A, const u16* Bk, const u16* Bv,
                                                 u16* Ck, u16* Cvp, int M, int N, int K) {
  const u16* B = blockIdx.z ? Bv : Bk;
  u16* C = blockIdx.z ? Cvp : Ck;
  gemm_core<1>(A, B, C, M, N, K, blockIdx.y * 128, blockIdx.x * 128);
}

// ---------------- RMSNorm(offset) + RoPE (+ optional post-scale), in place ----------------
__global__ __launch_bounds__(256) void k_normrope(u16* __restrict__ buf,
                                                  const float* __restrict__ cosb,
                                                  const float* __restrict__ sinb,
                                                  const float* __restrict__ w,
                                                  int nheads, int rowstride, int headstride,
                                                  int total, float post_scale) {
  int wid = blockIdx.x * 4 + (threadIdx.x >> 6);
  int lane = threadIdx.x & 63;
  int t = wid / nheads, h = wid - t * nheads;
  if (t >= total) return;
  u16* base = buf + (size_t)t * rowstride + h * headstride;
  float a = b2f(base[lane]), b = b2f(base[lane + 64]);
  float ss = a * a + b * b;
#pragma unroll
  for (int m = 32; m >= 1; m >>= 1) ss += __shfl_xor(ss, m, 64);
  float r = rsqrtf(ss * (1.0f / 128.0f) + 1e-6f);
  float qa = (1.0f + w[lane]) * a * r;
  float qb = (1.0f + w[lane + 64]) * b * r;
  const float* cr = cosb + (size_t)t * 128;
  const float* sr = sinb + (size_t)t * 128;
  float oa = (qa * cr[lane] - qb * sr[lane]) * post_scale;
  float ob = (qb * cr[lane + 64] + qa * sr[lane + 64]) * post_scale;
  base[lane] = f2b(oa);
  base[lane + 64] = f2b(ob);
}

// ---------------- transpose (rows x cols) -> (cols x rows), bf16 ----------------
__global__ __launch_bounds__(256) void k_transpose(const u16* __restrict__ src,
                                                   u16* __restrict__ dst, int rows, int cols) {
  __shared__ u16 tile[32][33];
  int bx = blockIdx.x * 32, by = blockIdx.y * 32;
  int tx = threadIdx.x & 31, ty = threadIdx.x >> 5;
#pragma unroll
  for (int i = 0; i < 4; ++i)
    tile[ty + i * 8][tx] = src[(size_t)(bx + ty + i * 8) * cols + by + tx];
  __syncthreads();
#pragma unroll
  for (int i = 0; i < 4; ++i)
    dst[(size_t)(by + ty + i * 8) * rows + bx + tx] = tile[tx][ty + i * 8];
}

// ---------------- flash attention + gate (swapped QK^T, O^T PV, in-lane softmax) -----------
// grid(total/64, H). 4 waves/block, each wave owns 16 q-rows. KV tiles of 32.
// q already pre-scaled by (1/sqrt(D))*log2(e), so softmax uses exp2.
__global__ __launch_bounds__(256) void k_attn(const u16* __restrict__ qg,  // total x 4096
                                              const u16* __restrict__ kb,  // total x 512
                                              const u16* __restrict__ vt,  // 512 x total
                                              u16* __restrict__ outg,      // total x 2048
                                              const int* __restrict__ cu, int n_seq, int total) {
  __shared__ __align__(16) u16 Ps[4][16][32];  // per-wave P tile [q][kv]
  const int tid = threadIdx.x, lane = tid & 63, w = tid >> 6;
  const int h = blockIdx.y, kh = h >> 2;
  const int g = lane >> 4, l15 = lane & 15;

  // heavy-first q-tile remap (causal: deepest tiles dispatched first)
  int bx = blockIdx.x, nt = gridDim.x, qt = bx;
  int per = total / n_seq;
  if (per * n_seq == total && (per & 63) == 0 && nt % n_seq == 0) {
    int tps = per >> 6;
    int seg = bx % n_seq;
    int p = tps - 1 - bx / n_seq;
    qt = seg * tps + p;
  }
  const int qr0 = qt * 64 + w * 16;

  int seg_start = 0, seg_end = total;
  for (int s = 0; s < n_seq; ++s) {
    int a = cu[s], b = cu[s + 1];
    if (qr0 >= a && qr0 < b) { seg_start = a; seg_end = b; }
  }

  // Q as B-fragment: col = q = l15, k = d
  bf16x8 qf[4];
#pragma unroll
  for (int cc = 0; cc < 4; ++cc)
    qf[cc] = *reinterpret_cast<const bf16x8*>(qg + (size_t)(qr0 + l15) * 4096 + h * 256 + cc * 32 + g * 8);

  f32x4 o[8] = {};               // O^T: lane q = l15, d = db*16 + g*4 + reg
  float mrow = -1e30f, lrow = 0.f;  // per-lane stats for q = l15 (groups agree)
  const int qrow = qr0 + l15;
  const int kv_end = (seg_end < qr0 + 16) ? seg_end : (qr0 + 16);

  for (int kv0 = seg_start; kv0 < kv_end; kv0 += 32) {
    f32x4 s0 = {}, s1 = {};      // S^T: col = q = l15, row = kv = g*4+reg (+16 for s1)
#pragma unroll
    for (int cc = 0; cc < 4; ++cc) {
      bf16x8 kf0 = *reinterpret_cast<const bf16x8*>(kb + (size_t)(kv0 + l15) * 512 + kh * 128 + cc * 32 + g * 8);
      bf16x8 kf1 = *reinterpret_cast<const bf16x8*>(kb + (size_t)(kv0 + 16 + l15) * 512 + kh * 128 + cc * 32 + g * 8);
      s0 = __builtin_amdgcn_mfma_f32_16x16x32_bf16(kf0, qf[cc], s0, 0, 0, 0);
      s1 = __builtin_amdgcn_mfma_f32_16x16x32_bf16(kf1, qf[cc], s1, 0, 0, 0);
    }
    // mask + in-lane max over the lane's 8 kv values
    float sv[8];
#pragma unroll
    for (int j = 0; j < 4; ++j) {
      sv[j]     = (kv0      + g * 4 + j > qrow) ? -1e30f : s0[j];
      sv[4 + j] = (kv0 + 16 + g * 4 + j > qrow) ? -1e30f : s1[j];
    }
    float pm = sv[0];
#pragma unroll
    for (int j = 1; j < 8; ++j) pm = fmaxf(pm, sv[j]);
    pm = fmaxf(pm, __shfl_xor(pm, 16));
    pm = fmaxf(pm, __shfl_xor(pm, 32));
    // defer-max: only rescale when max grew by > 8 nats (11.5 in log2 domain)
    if (pm > mrow + 11.5f) {
      float fs = __builtin_amdgcn_exp2f(mrow - pm);
      lrow *= fs;
#pragma unroll
      for (int db = 0; db < 8; ++db)
#pragma unroll
        for (int j = 0; j < 4; ++j) o[db][j] *= fs;
      mrow = pm;
    }
    float p[8];
#pragma unroll
    for (int j = 0; j < 8; ++j) p[j] = __builtin_amdgcn_exp2f(sv[j] - mrow);
    float ps = 0.f;
#pragma unroll
    for (int j = 0; j < 8; ++j) ps += p[j];
    ps += __shfl_xor(ps, 16);
    ps += __shfl_xor(ps, 32);
    lrow += ps;
    // P tile [q][kv] to LDS: 2x ds_write_b64 per lane
    uint2 w0 = { pk2(p[0], p[1]), pk2(p[2], p[3]) };
    uint2 w1 = { pk2(p[4], p[5]), pk2(p[6], p[7]) };
    *reinterpret_cast<uint2*>(&Ps[w][l15][g * 4]) = w0;
    *reinterpret_cast<uint2*>(&Ps[w][l15][16 + g * 4]) = w1;
    asm volatile("" ::: "memory");  // keep write before read (in-wave DS ordering)
    bf16x8 pf = *reinterpret_cast<const bf16x8*>(&Ps[w][l15][g * 8]);  // B: col=q=l15, k=kv
#pragma unroll
    for (int db = 0; db < 8; ++db) {
      bf16x8 vf = *reinterpret_cast<const bf16x8*>(vt + (size_t)(kh * 128 + db * 16 + l15) * total + kv0 + g * 8);
      o[db] = __builtin_amdgcn_mfma_f32_16x16x32_bf16(vf, pf, o[db], 0, 0, 0);  // O^T
    }
  }

  const float inv_l = 1.0f / lrow;
#pragma unroll
  for (int db = 0; db < 8; ++db) {
    int dbase = db * 16 + g * 4;
    const u16* gptr = qg + (size_t)qrow * 4096 + h * 256 + 128 + dbase;
    uint2 gw = *reinterpret_cast<const uint2*>(gptr);
    u16 gu[4] = { (u16)(gw.x & 0xffff), (u16)(gw.x >> 16), (u16)(gw.y & 0xffff), (u16)(gw.y >> 16) };
    u16 ou[4];
#pragma unroll
    for (int j = 0; j < 4; ++j) {
      float gate = b2f(gu[j]);
      float sig = 1.0f / (1.0f + __expf(-gate));
      ou[j] = f2b(o[db][j] * inv_l * sig);
    }
    *reinterpret_cast<uint2*>(outg + (size_t)qrow * 2048 + h * 128 + dbase) =
        *reinterpret_cast<uint2*>(ou);
  }
}

extern "C" void kernel_launch(void* const* d_in, const int* in_sizes, int n_in,
                              void* d_out, int out_size, void* d_ws, size_t ws_size,
                              hipStream_t stream) {
  const float* x    = (const float*)d_in[0];
  const float* cosb = (const float*)d_in[1];
  const float* sinb = (const float*)d_in[2];
  const float* Wq   = (const float*)d_in[3];
  const float* Wk   = (const float*)d_in[4];
  const float* Wv   = (const float*)d_in[5];
  const float* Wo   = (const float*)d_in[6];
  const float* qnw  = (const float*)d_in[7];
  const float* knw  = (const float*)d_in[8];
  const int*   cu   = (const int*)d_in[9];
  const int n_seq = in_sizes[9] - 1;

  const int hidden = 2048, H = 16, KVH = 4, D = 128;
  const int total = in_sizes[0] / hidden;  // 4096
  const int NQ = H * D * 2;                // 4096
  const int NKV = KVH * D;                 // 512

  char* ws = (char*)d_ws;
  size_t off = 0;
  auto alloc = [&](size_t elems) {
    u16* p = (u16*)(ws + off);
    off += elems * 2;
    off = (off + 255) & ~(size_t)255;
    return p;
  };
  u16* xb   = alloc((size_t)total * hidden);
  u16* Wqb  = alloc((size_t)NQ * hidden);
  u16* Wkb  = alloc((size_t)NKV * hidden);
  u16* Wvb  = alloc((size_t)NKV * hidden);
  u16* Wob  = alloc((size_t)hidden * (H * D));
  u16* qgb  = alloc((size_t)total * NQ);
  u16* kbuf = alloc((size_t)total * NKV);
  u16* vbuf = alloc((size_t)total * NKV);
  u16* vtb  = alloc((size_t)total * NKV);
  u16* attg = Wqb;  // alias: Wqb dead after GEMM1

  auto cgrid = [](int n) { int g = (n / 4 + 255) / 256; return g > 2048 ? 2048 : g; };
  k_f2b<<<cgrid(total * hidden), 256, 0, stream>>>(x, xb, total * hidden);
  k_f2b<<<cgrid(NQ * hidden), 256, 0, stream>>>(Wq, Wqb, NQ * hidden);
  k_f2b<<<cgrid(NKV * hidden), 256, 0, stream>>>(Wk, Wkb, NKV * hidden);
  k_f2b<<<cgrid(NKV * hidden), 256, 0, stream>>>(Wv, Wvb, NKV * hidden);
  k_f2b<<<cgrid(hidden * H * D), 256, 0, stream>>>(Wo, Wob, hidden * H * D);

  k_gemm_bf16<<<dim3(NQ / 128, total / 128), 256, 0, stream>>>(xb, Wqb, qgb, total, NQ, hidden);
  k_gemm_kv<<<dim3(NKV / 128, total / 128, 2), 256, 0, stream>>>(xb, Wkb, Wvb, kbuf, vbuf,
                                                                 total, NKV, hidden);
  k_transpose<<<dim3(total / 32, NKV / 32), 256, 0, stream>>>(vbuf, vtb, total, NKV);
  // q: fold softmax scale and log2(e) so attention uses exp2 directly
  const float qscale = 0.08838834764831845f * 1.4426950408889634f;
  k_normrope<<<total * H / 4, 256, 0, stream>>>(qgb, cosb, sinb, qnw, H, NQ, 2 * D, total, qscale);
  k_normrope<<<total * KVH / 4, 256, 0, stream>>>(kbuf, cosb, sinb, knw, KVH, NKV, D, total, 1.0f);
  k_attn<<<dim3(total / 64, H), 256, 0, stream>>>(qgb, kbuf, vtb, attg, cu, n_seq, total);
  k_gemm_f32<<<dim3(hidden / 128, total / 128), 256, 0, stream>>>(attg, Wob, (float*)d_out,
                                                                  total, hidden, H * D);
}

// Round 3
// 387.632 us; speedup vs baseline: 1.2584x; 1.1152x over previous
//
#include <hip/hip_runtime.h>
#include <stdint.h>

typedef unsigned short u16;
typedef __bf16 bf16_t;
typedef bf16_t bf16x8 __attribute__((ext_vector_type(8)));
typedef float f32x4 __attribute__((ext_vector_type(4)));

__device__ __forceinline__ float b2f(u16 u) {
  union { unsigned int i; float f; } v; v.i = ((unsigned int)u) << 16; return v.f;
}
__device__ __forceinline__ u16 f2b(float f) {
  union { float f; unsigned int i; } v; v.f = f;
  unsigned int r = v.i + 0x7fffu + ((v.i >> 16) & 1u);  // RNE
  return (u16)(r >> 16);
}
__device__ __forceinline__ unsigned int pk2(float a, float b) {
  return (unsigned int)f2b(a) | ((unsigned int)f2b(b) << 16);
}
__device__ __forceinline__ void async16(const void* g, void* lds) {
  __builtin_amdgcn_global_load_lds((const __attribute__((address_space(1))) void*)g,
                                   (__attribute__((address_space(3))) void*)lds,
                                   16, 0, 0);
}

// ---------------- fp32 -> bf16 conversion ----------------
__global__ void k_f2b(const float* __restrict__ src, u16* __restrict__ dst, int n) {
  int i = (blockIdx.x * 256 + threadIdx.x) * 4;
  int stride = gridDim.x * 256 * 4;
  for (; i < n; i += stride) {
    float4 v = *reinterpret_cast<const float4*>(src + i);
    u16 o[4] = { f2b(v.x), f2b(v.y), f2b(v.z), f2b(v.w) };
    *reinterpret_cast<uint2*>(dst + i) = *reinterpret_cast<uint2*>(o);
  }
}

// ---------------- GEMM: C = A(MxK) * B(NxK)^T, bf16 in, f32 or bf16 out ----------------
template<int OUT_BF16>
__device__ __forceinline__ void gemm_core(const u16* __restrict__ A, const u16* __restrict__ B,
                                          void* __restrict__ Cv, int M, int N, int K,
                                          int m0, int n0) {
  __shared__ __align__(16) u16 As[128 * 32];
  __shared__ __align__(16) u16 Bs[128 * 32];
  const int tid = threadIdx.x, lane = tid & 63, w = tid >> 6;
  const int wr = (w >> 1) * 64, wc = (w & 1) * 64;
  const int lr = lane & 15, lk = (lane >> 4) * 8;
  f32x4 acc[4][4] = {};
  for (int k0 = 0; k0 < K; k0 += 32) {
    if (k0) __syncthreads();
#pragma unroll
    for (int it = 0; it < 2; ++it) {
      int c = it * 256 + tid;
      int row = c >> 2, kc = (c & 3) * 8;
      async16(A + (size_t)(m0 + row) * K + k0 + kc, (char*)As + c * 16);
      async16(B + (size_t)(n0 + row) * K + k0 + kc, (char*)Bs + c * 16);
    }
    __syncthreads();
    bf16x8 af[4], bfr[4];
#pragma unroll
    for (int i = 0; i < 4; ++i)
      af[i] = *reinterpret_cast<const bf16x8*>(&As[(wr + i * 16 + lr) * 32 + lk]);
#pragma unroll
    for (int i = 0; i < 4; ++i)
      bfr[i] = *reinterpret_cast<const bf16x8*>(&Bs[(wc + i * 16 + lr) * 32 + lk]);
#pragma unroll
    for (int i = 0; i < 4; ++i)
#pragma unroll
      for (int j = 0; j < 4; ++j)
        acc[i][j] = __builtin_amdgcn_mfma_f32_16x16x32_bf16(af[i], bfr[j], acc[i][j], 0, 0, 0);
  }
  const int er = (lane >> 4) * 4, ec = lane & 15;
#pragma unroll
  for (int i = 0; i < 4; ++i)
#pragma unroll
    for (int j = 0; j < 4; ++j)
#pragma unroll
      for (int jj = 0; jj < 4; ++jj) {
        int r = m0 + wr + i * 16 + er + jj;
        int cc = n0 + wc + j * 16 + ec;
        if (OUT_BF16) ((u16*)Cv)[(size_t)r * N + cc] = f2b(acc[i][j][jj]);
        else          ((float*)Cv)[(size_t)r * N + cc] = acc[i][j][jj];
      }
}

__global__ __launch_bounds__(256) void k_gemm_bf16(const u16* A, const u16* B, u16* C,
                                                   int M, int N, int K) {
  gemm_core<1>(A, B, C, M, N, K, blockIdx.y * 128, blockIdx.x * 128);
}
__global__ __launch_bounds__(256) void k_gemm_f32(const u16* A, const u16* B, float* C,
                                                  int M, int N, int K) {
  gemm_core<0>(A, B, C, M, N, K, blockIdx.y * 128, blockIdx.x * 128);
}
__global__ __launch_bounds__(256) void k_gemm_kv(const u16* A, const u16* Bk, const u16* Bv,
                                                 u16* Ck, u16* Cvp, int M, int N, int K) {
  const u16* B = blockIdx.z ? Bv : Bk;
  u16* C = blockIdx.z ? Cvp : Ck;
  gemm_core<1>(A, B, C, M, N, K, blockIdx.y * 128, blockIdx.x * 128);
}

// ---------------- RMSNorm(offset) + RoPE (+ optional post-scale), in place ----------------
__global__ __launch_bounds__(256) void k_normrope(u16* __restrict__ buf,
                                                  const float* __restrict__ cosb,
                                                  const float* __restrict__ sinb,
                                                  const float* __restrict__ w,
                                                  int nheads, int rowstride, int headstride,
                                                  int total, float post_scale) {
  int wid = blockIdx.x * 4 + (threadIdx.x >> 6);
  int lane = threadIdx.x & 63;
  int t = wid / nheads, h = wid - t * nheads;
  if (t >= total) return;
  u16* base = buf + (size_t)t * rowstride + h * headstride;
  float a = b2f(base[lane]), b = b2f(base[lane + 64]);
  float ss = a * a + b * b;
#pragma unroll
  for (int m = 32; m >= 1; m >>= 1) ss += __shfl_xor(ss, m, 64);
  float r = rsqrtf(ss * (1.0f / 128.0f) + 1e-6f);
  float qa = (1.0f + w[lane]) * a * r;
  float qb = (1.0f + w[lane + 64]) * b * r;
  const float* cr = cosb + (size_t)t * 128;
  const float* sr = sinb + (size_t)t * 128;
  float oa = (qa * cr[lane] - qb * sr[lane]) * post_scale;
  float ob = (qb * cr[lane + 64] + qa * sr[lane + 64]) * post_scale;
  base[lane] = f2b(oa);
  base[lane + 64] = f2b(ob);
}

// ---------------- transpose (rows x cols) -> (cols x rows), bf16 ----------------
__global__ __launch_bounds__(256) void k_transpose(const u16* __restrict__ src,
                                                   u16* __restrict__ dst, int rows, int cols) {
  __shared__ u16 tile[32][33];
  int bx = blockIdx.x * 32, by = blockIdx.y * 32;
  int tx = threadIdx.x & 31, ty = threadIdx.x >> 5;
#pragma unroll
  for (int i = 0; i < 4; ++i)
    tile[ty + i * 8][tx] = src[(size_t)(bx + ty + i * 8) * cols + by + tx];
  __syncthreads();
#pragma unroll
  for (int i = 0; i < 4; ++i)
    dst[(size_t)(by + ty + i * 8) * rows + bx + tx] = tile[tx][ty + i * 8];
}

// ---------------- flash attention + gate: split-KV across the 4 waves of a block ----------
// grid(total/16, H). Block = 16 q-rows of one head. All 4 waves share the q rows and
// round-robin the KV tiles (t = w, w+4, ...); partial (m, l, O^T) merged in LDS at the end.
// q pre-scaled by (1/sqrt(D))*log2(e) so softmax is exp2-domain.
__global__ __launch_bounds__(256) void k_attn(const u16* __restrict__ qg,  // total x 4096
                                              const u16* __restrict__ kb,  // total x 512
                                              const u16* __restrict__ vt,  // 512 x total
                                              u16* __restrict__ outg,      // total x 2048
                                              const int* __restrict__ cu, int n_seq, int total) {
  __shared__ __align__(16) u16 Ps[4][16][40];      // per-wave P tile [q][kv], padded rows
  __shared__ __align__(16) float Lo[4][16][128];   // per-wave partial O^T
  __shared__ float Lm[4][16], Ll[4][16];
  const int tid = threadIdx.x, lane = tid & 63, w = tid >> 6;
  const int h = blockIdx.y, kh = h >> 2;
  const int g = lane >> 4, l15 = lane & 15;

  // heavy-first q-tile remap (deepest causal tiles dispatched first)
  int bx = blockIdx.x, nt = gridDim.x, qt = bx;
  int per = total / n_seq;
  if (per * n_seq == total && (per & 15) == 0 && nt % n_seq == 0) {
    int tps = per >> 4;
    int seg = bx % n_seq;
    qt = seg * tps + (tps - 1 - bx / n_seq);
  }
  const int qr0 = qt * 16;

  int seg_start = 0, seg_end = total;
  for (int s = 0; s < n_seq; ++s) {
    int a = cu[s], b = cu[s + 1];
    if (qr0 >= a && qr0 < b) { seg_start = a; seg_end = b; }
  }
  const int qrow = qr0 + l15;

  // Q as B-fragment: col = q = l15, k = d
  bf16x8 qf[4];
#pragma unroll
  for (int cc = 0; cc < 4; ++cc)
    qf[cc] = *reinterpret_cast<const bf16x8*>(qg + (size_t)qrow * 4096 + h * 256 + cc * 32 + g * 8);

  f32x4 o[8] = {};                  // O^T partial: lane q = l15, d = db*16 + g*4 + reg
  float mrow = -1e30f, lrow = 0.f;  // per-q stats (consistent across the 4 lane groups)
  const int kv_hi = (seg_end < qr0 + 16) ? seg_end : (qr0 + 16);
  const int ntiles = (kv_hi - seg_start + 31) >> 5;

  for (int t = w; t < ntiles; t += 4) {
    const int kv0 = seg_start + t * 32;
    f32x4 s0 = {}, s1 = {};         // S^T: col = q = l15, row = kv = g*4+reg (+16 for s1)
#pragma unroll
    for (int cc = 0; cc < 4; ++cc) {
      bf16x8 kf0 = *reinterpret_cast<const bf16x8*>(kb + (size_t)(kv0 + l15) * 512 + kh * 128 + cc * 32 + g * 8);
      bf16x8 kf1 = *reinterpret_cast<const bf16x8*>(kb + (size_t)(kv0 + 16 + l15) * 512 + kh * 128 + cc * 32 + g * 8);
      s0 = __builtin_amdgcn_mfma_f32_16x16x32_bf16(kf0, qf[cc], s0, 0, 0, 0);
      s1 = __builtin_amdgcn_mfma_f32_16x16x32_bf16(kf1, qf[cc], s1, 0, 0, 0);
    }
    float sv[8];
#pragma unroll
    for (int j = 0; j < 4; ++j) {
      sv[j]     = (kv0      + g * 4 + j > qrow) ? -1e30f : s0[j];
      sv[4 + j] = (kv0 + 16 + g * 4 + j > qrow) ? -1e30f : s1[j];
    }
    float pm = sv[0];
#pragma unroll
    for (int j = 1; j < 8; ++j) pm = fmaxf(pm, sv[j]);
    pm = fmaxf(pm, __shfl_xor(pm, 16));
    pm = fmaxf(pm, __shfl_xor(pm, 32));
    if (pm > mrow + 11.5f) {        // defer-max (~8 nats in log2 domain)
      float fs = __builtin_amdgcn_exp2f(mrow - pm);
      lrow *= fs;
#pragma unroll
      for (int db = 0; db < 8; ++db)
#pragma unroll
        for (int j = 0; j < 4; ++j) o[db][j] *= fs;
      mrow = pm;
    }
    float p[8];
#pragma unroll
    for (int j = 0; j < 8; ++j)
      p[j] = (sv[j] > -1e29f) ? __builtin_amdgcn_exp2f(sv[j] - mrow) : 0.0f;
    float ps = 0.f;
#pragma unroll
    for (int j = 0; j < 8; ++j) ps += p[j];
    ps += __shfl_xor(ps, 16);
    ps += __shfl_xor(ps, 32);
    lrow += ps;
    uint2 w0 = { pk2(p[0], p[1]), pk2(p[2], p[3]) };
    uint2 w1 = { pk2(p[4], p[5]), pk2(p[6], p[7]) };
    *reinterpret_cast<uint2*>(&Ps[w][l15][g * 4]) = w0;
    *reinterpret_cast<uint2*>(&Ps[w][l15][16 + g * 4]) = w1;
    asm volatile("" ::: "memory");  // in-wave DS write->read ordering
    bf16x8 pf = *reinterpret_cast<const bf16x8*>(&Ps[w][l15][g * 8]);  // B: col=q, k=kv
#pragma unroll
    for (int db = 0; db < 8; ++db) {
      bf16x8 vf = *reinterpret_cast<const bf16x8*>(vt + (size_t)(kh * 128 + db * 16 + l15) * total + kv0 + g * 8);
      o[db] = __builtin_amdgcn_mfma_f32_16x16x32_bf16(vf, pf, o[db], 0, 0, 0);  // O^T
    }
  }

  // publish partials
#pragma unroll
  for (int db = 0; db < 8; ++db)
    *reinterpret_cast<f32x4*>(&Lo[w][l15][db * 16 + g * 4]) = o[db];
  if (g == 0) { Lm[w][l15] = mrow; Ll[w][l15] = lrow; }
  __syncthreads();

  // combine: thread -> (q = tid&15, d block = (tid>>4)*8)
  const int q = tid & 15, dg = tid >> 4;
  float m0 = Lm[0][q], m1 = Lm[1][q], m2 = Lm[2][q], m3 = Lm[3][q];
  float M = fmaxf(fmaxf(m0, m1), fmaxf(m2, m3));
  float r0 = exp2f(m0 - M), r1 = exp2f(m1 - M), r2 = exp2f(m2 - M), r3 = exp2f(m3 - M);
  float L = Ll[0][q] * r0 + Ll[1][q] * r1 + Ll[2][q] * r2 + Ll[3][q] * r3;
  float invL = 1.0f / L;
  const int row = qr0 + q;
  const u16* gp = qg + (size_t)row * 4096 + h * 256 + 128 + dg * 8;
  uint4 gw = *reinterpret_cast<const uint4*>(gp);
  u16 gu[8] = { (u16)(gw.x & 0xffff), (u16)(gw.x >> 16), (u16)(gw.y & 0xffff), (u16)(gw.y >> 16),
                (u16)(gw.z & 0xffff), (u16)(gw.z >> 16), (u16)(gw.w & 0xffff), (u16)(gw.w >> 16) };
  u16 ou[8];
#pragma unroll
  for (int j = 0; j < 8; ++j) {
    int d = dg * 8 + j;
    float s = Lo[0][q][d] * r0 + Lo[1][q][d] * r1 + Lo[2][q][d] * r2 + Lo[3][q][d] * r3;
    float gate = b2f(gu[j]);
    float sig = 1.0f / (1.0f + __expf(-gate));
    ou[j] = f2b(s * invL * sig);
  }
  *reinterpret_cast<uint4*>(outg + (size_t)row * 2048 + h * 128 + dg * 8) =
      *reinterpret_cast<uint4*>(ou);
}

extern "C" void kernel_launch(void* const* d_in, const int* in_sizes, int n_in,
                              void* d_out, int out_size, void* d_ws, size_t ws_size,
                              hipStream_t stream) {
  const float* x    = (const float*)d_in[0];
  const float* cosb = (const float*)d_in[1];
  const float* sinb = (const float*)d_in[2];
  const float* Wq   = (const float*)d_in[3];
  const float* Wk   = (const float*)d_in[4];
  const float* Wv   = (const float*)d_in[5];
  const float* Wo   = (const float*)d_in[6];
  const float* qnw  = (const float*)d_in[7];
  const float* knw  = (const float*)d_in[8];
  const int*   cu   = (const int*)d_in[9];
  const int n_seq = in_sizes[9] - 1;

  const int hidden = 2048, H = 16, KVH = 4, D = 128;
  const int total = in_sizes[0] / hidden;  // 4096
  const int NQ = H * D * 2;                // 4096
  const int NKV = KVH * D;                 // 512

  char* ws = (char*)d_ws;
  size_t off = 0;
  auto alloc = [&](size_t elems) {
    u16* p = (u16*)(ws + off);
    off += elems * 2;
    off = (off + 255) & ~(size_t)255;
    return p;
  };
  u16* xb   = alloc((size_t)total * hidden);
  u16* Wqb  = alloc((size_t)NQ * hidden);
  u16* Wkb  = alloc((size_t)NKV * hidden);
  u16* Wvb  = alloc((size_t)NKV * hidden);
  u16* Wob  = alloc((size_t)hidden * (H * D));
  u16* qgb  = alloc((size_t)total * NQ);
  u16* kbuf = alloc((size_t)total * NKV);
  u16* vbuf = alloc((size_t)total * NKV);
  u16* vtb  = alloc((size_t)total * NKV);
  u16* attg = Wqb;  // alias: Wqb dead after GEMM1

  auto cgrid = [](int n) { int g = (n / 4 + 255) / 256; return g > 2048 ? 2048 : g; };
  k_f2b<<<cgrid(total * hidden), 256, 0, stream>>>(x, xb, total * hidden);
  k_f2b<<<cgrid(NQ * hidden), 256, 0, stream>>>(Wq, Wqb, NQ * hidden);
  k_f2b<<<cgrid(NKV * hidden), 256, 0, stream>>>(Wk, Wkb, NKV * hidden);
  k_f2b<<<cgrid(NKV * hidden), 256, 0, stream>>>(Wv, Wvb, NKV * hidden);
  k_f2b<<<cgrid(hidden * H * D), 256, 0, stream>>>(Wo, Wob, hidden * H * D);

  k_gemm_bf16<<<dim3(NQ / 128, total / 128), 256, 0, stream>>>(xb, Wqb, qgb, total, NQ, hidden);
  k_gemm_kv<<<dim3(NKV / 128, total / 128, 2), 256, 0, stream>>>(xb, Wkb, Wvb, kbuf, vbuf,
                                                                 total, NKV, hidden);
  k_transpose<<<dim3(total / 32, NKV / 32), 256, 0, stream>>>(vbuf, vtb, total, NKV);
  const float qscale = 0.08838834764831845f * 1.4426950408889634f;  // 1/sqrt(D) * log2(e)
  k_normrope<<<total * H / 4, 256, 0, stream>>>(qgb, cosb, sinb, qnw, H, NQ, 2 * D, total, qscale);
  k_normrope<<<total * KVH / 4, 256, 0, stream>>>(kbuf, cosb, sinb, knw, KVH, NKV, D, total, 1.0f);
  k_attn<<<dim3(total / 16, H), 256, 0, stream>>>(qgb, kbuf, vtb, attg, cu, n_seq, total);
  k_gemm_f32<<<dim3(hidden / 128, total / 128), 256, 0, stream>>>(attg, Wob, (float*)d_out,
                                                                  total, hidden, H * D);
}

// Round 4
// 381.511 us; speedup vs baseline: 1.2786x; 1.0160x over previous
//
#include <hip/hip_runtime.h>
#include <stdint.h>

typedef unsigned short u16;
typedef __bf16 bf16_t;
typedef bf16_t bf16x8 __attribute__((ext_vector_type(8)));
typedef float f32x4 __attribute__((ext_vector_type(4)));

__device__ __forceinline__ float b2f(u16 u) {
  union { unsigned int i; float f; } v; v.i = ((unsigned int)u) << 16; return v.f;
}
__device__ __forceinline__ u16 f2b(float f) {
  union { float f; unsigned int i; } v; v.f = f;
  unsigned int r = v.i + 0x7fffu + ((v.i >> 16) & 1u);  // RNE
  return (u16)(r >> 16);
}
__device__ __forceinline__ unsigned int pk2(float a, float b) {
  return (unsigned int)f2b(a) | ((unsigned int)f2b(b) << 16);
}
__device__ __forceinline__ void async16(const void* g, void* lds) {
  __builtin_amdgcn_global_load_lds((const __attribute__((address_space(1))) void*)g,
                                   (__attribute__((address_space(3))) void*)lds,
                                   16, 0, 0);
}

// ---------------- fp32 -> bf16 conversion ----------------
__global__ void k_f2b(const float* __restrict__ src, u16* __restrict__ dst, int n) {
  int i = (blockIdx.x * 256 + threadIdx.x) * 4;
  int stride = gridDim.x * 256 * 4;
  for (; i < n; i += stride) {
    float4 v = *reinterpret_cast<const float4*>(src + i);
    u16 o[4] = { f2b(v.x), f2b(v.y), f2b(v.z), f2b(v.w) };
    *reinterpret_cast<uint2*>(dst + i) = *reinterpret_cast<uint2*>(o);
  }
}

// ---------------- GEMM: C = A(MxK) * B(NxK)^T, bf16 in, f32 or bf16 out ----------------
// 128x128 tile, BK=32, 4 waves, mfma_f32_16x16x32_bf16, global_load_lds staging.
// XCD-aware block swizzle (bijective since nwg % 8 == 0 for all our shapes).
__device__ __forceinline__ void xcd_tile(int ntx, int* m0, int* n0) {
  int id = blockIdx.y * ntx + blockIdx.x;
  int nwg = ntx * gridDim.y;
  if ((nwg & 7) == 0) {
    int q = nwg >> 3;
    id = (id & 7) * q + (id >> 3);
  }
  *m0 = (id / ntx) * 128;
  *n0 = (id % ntx) * 128;
}

template<int OUT_BF16>
__device__ __forceinline__ void gemm_core(const u16* __restrict__ A, const u16* __restrict__ B,
                                          void* __restrict__ Cv, int M, int N, int K,
                                          int m0, int n0) {
  __shared__ __align__(16) u16 As[128 * 32];
  __shared__ __align__(16) u16 Bs[128 * 32];
  const int tid = threadIdx.x, lane = tid & 63, w = tid >> 6;
  const int wr = (w >> 1) * 64, wc = (w & 1) * 64;
  const int lr = lane & 15, lk = (lane >> 4) * 8;
  f32x4 acc[4][4] = {};
  for (int k0 = 0; k0 < K; k0 += 32) {
    if (k0) __syncthreads();
#pragma unroll
    for (int it = 0; it < 2; ++it) {
      int c = it * 256 + tid;
      int row = c >> 2, kc = (c & 3) * 8;
      async16(A + (size_t)(m0 + row) * K + k0 + kc, (char*)As + c * 16);
      async16(B + (size_t)(n0 + row) * K + k0 + kc, (char*)Bs + c * 16);
    }
    __syncthreads();
    bf16x8 af[4], bfr[4];
#pragma unroll
    for (int i = 0; i < 4; ++i)
      af[i] = *reinterpret_cast<const bf16x8*>(&As[(wr + i * 16 + lr) * 32 + lk]);
#pragma unroll
    for (int i = 0; i < 4; ++i)
      bfr[i] = *reinterpret_cast<const bf16x8*>(&Bs[(wc + i * 16 + lr) * 32 + lk]);
#pragma unroll
    for (int i = 0; i < 4; ++i)
#pragma unroll
      for (int j = 0; j < 4; ++j)
        acc[i][j] = __builtin_amdgcn_mfma_f32_16x16x32_bf16(af[i], bfr[j], acc[i][j], 0, 0, 0);
  }
  const int er = (lane >> 4) * 4, ec = lane & 15;
#pragma unroll
  for (int i = 0; i < 4; ++i)
#pragma unroll
    for (int j = 0; j < 4; ++j)
#pragma unroll
      for (int jj = 0; jj < 4; ++jj) {
        int r = m0 + wr + i * 16 + er + jj;
        int cc = n0 + wc + j * 16 + ec;
        if (OUT_BF16) ((u16*)Cv)[(size_t)r * N + cc] = f2b(acc[i][j][jj]);
        else          ((float*)Cv)[(size_t)r * N + cc] = acc[i][j][jj];
      }
}

__global__ __launch_bounds__(256) void k_gemm_bf16(const u16* A, const u16* B, u16* C,
                                                   int M, int N, int K) {
  int m0, n0; xcd_tile(gridDim.x, &m0, &n0);
  gemm_core<1>(A, B, C, M, N, K, m0, n0);
}
__global__ __launch_bounds__(256) void k_gemm_f32(const u16* A, const u16* B, float* C,
                                                  int M, int N, int K) {
  int m0, n0; xcd_tile(gridDim.x, &m0, &n0);
  gemm_core<0>(A, B, C, M, N, K, m0, n0);
}
__global__ __launch_bounds__(256) void k_gemm_kv(const u16* A, const u16* Bk, const u16* Bv,
                                                 u16* Ck, u16* Cvp, int M, int N, int K) {
  const u16* B = blockIdx.z ? Bv : Bk;
  u16* C = blockIdx.z ? Cvp : Ck;
  int m0, n0; xcd_tile(gridDim.x, &m0, &n0);
  gemm_core<1>(A, B, C, M, N, K, m0, n0);
}

// ---------------- RMSNorm(offset) + RoPE (+ optional post-scale), in place ----------------
__global__ __launch_bounds__(256) void k_normrope(u16* __restrict__ buf,
                                                  const float* __restrict__ cosb,
                                                  const float* __restrict__ sinb,
                                                  const float* __restrict__ w,
                                                  int nheads, int rowstride, int headstride,
                                                  int total, float post_scale) {
  int wid = blockIdx.x * 4 + (threadIdx.x >> 6);
  int lane = threadIdx.x & 63;
  int t = wid / nheads, h = wid - t * nheads;
  if (t >= total) return;
  u16* base = buf + (size_t)t * rowstride + h * headstride;
  float a = b2f(base[lane]), b = b2f(base[lane + 64]);
  float ss = a * a + b * b;
#pragma unroll
  for (int m = 32; m >= 1; m >>= 1) ss += __shfl_xor(ss, m, 64);
  float r = rsqrtf(ss * (1.0f / 128.0f) + 1e-6f);
  float qa = (1.0f + w[lane]) * a * r;
  float qb = (1.0f + w[lane + 64]) * b * r;
  const float* cr = cosb + (size_t)t * 128;
  const float* sr = sinb + (size_t)t * 128;
  float oa = (qa * cr[lane] - qb * sr[lane]) * post_scale;
  float ob = (qb * cr[lane + 64] + qa * sr[lane + 64]) * post_scale;
  base[lane] = f2b(oa);
  base[lane + 64] = f2b(ob);
}

// ---------------- transpose (rows x cols) -> (cols x rows), bf16 ----------------
__global__ __launch_bounds__(256) void k_transpose(const u16* __restrict__ src,
                                                   u16* __restrict__ dst, int rows, int cols) {
  __shared__ u16 tile[32][33];
  int bx = blockIdx.x * 32, by = blockIdx.y * 32;
  int tx = threadIdx.x & 31, ty = threadIdx.x >> 5;
#pragma unroll
  for (int i = 0; i < 4; ++i)
    tile[ty + i * 8][tx] = src[(size_t)(bx + ty + i * 8) * cols + by + tx];
  __syncthreads();
#pragma unroll
  for (int i = 0; i < 4; ++i)
    dst[(size_t)(by + ty + i * 8) * rows + bx + tx] = tile[tx][ty + i * 8];
}

// ---------------- flash attention + gate: split-KV across the 4 waves of a block ----------
// grid(total/16, H). Block = 16 q-rows of one head; waves round-robin KV tiles.
// Partials published to LDS in bf16 (padded rows -> no bank conflicts), merged by LSE.
__global__ __launch_bounds__(256) void k_attn(const u16* __restrict__ qg,  // total x 4096
                                              const u16* __restrict__ kb,  // total x 512
                                              const u16* __restrict__ vt,  // 512 x total
                                              u16* __restrict__ outg,      // total x 2048
                                              const int* __restrict__ cu, int n_seq, int total) {
  __shared__ __align__(16) u16 Ps[4][16][40];     // per-wave P tile [q][kv], padded rows
  __shared__ __align__(16) u16 Lo[4][16][136];    // per-wave partial O^T, bf16, padded rows
  __shared__ float Lm[4][16], Ll[4][16];
  const int tid = threadIdx.x, lane = tid & 63, w = tid >> 6;
  const int h = blockIdx.y, kh = h >> 2;
  const int g = lane >> 4, l15 = lane & 15;

  // heavy-first q-tile remap (deepest causal tiles dispatched first)
  int bx = blockIdx.x, nt = gridDim.x, qt = bx;
  int per = total / n_seq;
  if (per * n_seq == total && (per & 15) == 0 && nt % n_seq == 0) {
    int tps = per >> 4;
    int seg = bx % n_seq;
    qt = seg * tps + (tps - 1 - bx / n_seq);
  }
  const int qr0 = qt * 16;

  int seg_start = 0, seg_end = total;
  for (int s = 0; s < n_seq; ++s) {
    int a = cu[s], b = cu[s + 1];
    if (qr0 >= a && qr0 < b) { seg_start = a; seg_end = b; }
  }
  const int qrow = qr0 + l15;

  // Q as B-fragment: col = q = l15, k = d
  bf16x8 qf[4];
#pragma unroll
  for (int cc = 0; cc < 4; ++cc)
    qf[cc] = *reinterpret_cast<const bf16x8*>(qg + (size_t)qrow * 4096 + h * 256 + cc * 32 + g * 8);

  f32x4 o[8] = {};                  // O^T partial: lane q = l15, d = db*16 + g*4 + reg
  float mrow = -1e30f, lrow = 0.f;
  const int kv_hi = (seg_end < qr0 + 16) ? seg_end : (qr0 + 16);
  const int ntiles = (kv_hi - seg_start + 31) >> 5;

  for (int t = w; t < ntiles; t += 4) {
    const int kv0 = seg_start + t * 32;
    f32x4 s0 = {}, s1 = {};         // S^T: col = q = l15, row = kv = g*4+reg (+16 for s1)
#pragma unroll
    for (int cc = 0; cc < 4; ++cc) {
      bf16x8 kf0 = *reinterpret_cast<const bf16x8*>(kb + (size_t)(kv0 + l15) * 512 + kh * 128 + cc * 32 + g * 8);
      bf16x8 kf1 = *reinterpret_cast<const bf16x8*>(kb + (size_t)(kv0 + 16 + l15) * 512 + kh * 128 + cc * 32 + g * 8);
      s0 = __builtin_amdgcn_mfma_f32_16x16x32_bf16(kf0, qf[cc], s0, 0, 0, 0);
      s1 = __builtin_amdgcn_mfma_f32_16x16x32_bf16(kf1, qf[cc], s1, 0, 0, 0);
    }
    float sv[8];
#pragma unroll
    for (int j = 0; j < 4; ++j) {
      sv[j]     = (kv0      + g * 4 + j > qrow) ? -1e30f : s0[j];
      sv[4 + j] = (kv0 + 16 + g * 4 + j > qrow) ? -1e30f : s1[j];
    }
    float pm = sv[0];
#pragma unroll
    for (int j = 1; j < 8; ++j) pm = fmaxf(pm, sv[j]);
    pm = fmaxf(pm, __shfl_xor(pm, 16));
    pm = fmaxf(pm, __shfl_xor(pm, 32));
    if (pm > mrow + 11.5f) {        // defer-max (~8 nats, log2 domain)
      float fs = __builtin_amdgcn_exp2f(mrow - pm);
      lrow *= fs;
#pragma unroll
      for (int db = 0; db < 8; ++db)
#pragma unroll
        for (int j = 0; j < 4; ++j) o[db][j] *= fs;
      mrow = pm;
    }
    float p[8];
#pragma unroll
    for (int j = 0; j < 8; ++j)
      p[j] = (sv[j] > -1e29f) ? __builtin_amdgcn_exp2f(sv[j] - mrow) : 0.0f;
    float ps = 0.f;
#pragma unroll
    for (int j = 0; j < 8; ++j) ps += p[j];
    ps += __shfl_xor(ps, 16);
    ps += __shfl_xor(ps, 32);
    lrow += ps;
    uint2 w0 = { pk2(p[0], p[1]), pk2(p[2], p[3]) };
    uint2 w1 = { pk2(p[4], p[5]), pk2(p[6], p[7]) };
    *reinterpret_cast<uint2*>(&Ps[w][l15][g * 4]) = w0;
    *reinterpret_cast<uint2*>(&Ps[w][l15][16 + g * 4]) = w1;
    asm volatile("" ::: "memory");  // in-wave DS write->read ordering
    bf16x8 pf = *reinterpret_cast<const bf16x8*>(&Ps[w][l15][g * 8]);  // B: col=q, k=kv
#pragma unroll
    for (int db = 0; db < 8; ++db) {
      bf16x8 vf = *reinterpret_cast<const bf16x8*>(vt + (size_t)(kh * 128 + db * 16 + l15) * total + kv0 + g * 8);
      o[db] = __builtin_amdgcn_mfma_f32_16x16x32_bf16(vf, pf, o[db], 0, 0, 0);  // O^T
    }
  }

  // publish partials (bf16, padded rows: bank-conflict-free)
#pragma unroll
  for (int db = 0; db < 8; ++db) {
    uint2 pw = { pk2(o[db][0], o[db][1]), pk2(o[db][2], o[db][3]) };
    *reinterpret_cast<uint2*>(&Lo[w][l15][db * 16 + g * 4]) = pw;
  }
  if (g == 0) { Lm[w][l15] = mrow; Ll[w][l15] = lrow; }
  __syncthreads();

  // combine: thread -> (q = tid&15, d group = (tid>>4)*8)
  const int q = tid & 15, dg = tid >> 4;
  float m0 = Lm[0][q], m1 = Lm[1][q], m2 = Lm[2][q], m3 = Lm[3][q];
  float M = fmaxf(fmaxf(m0, m1), fmaxf(m2, m3));
  float r0 = exp2f(m0 - M), r1 = exp2f(m1 - M), r2 = exp2f(m2 - M), r3 = exp2f(m3 - M);
  float L = Ll[0][q] * r0 + Ll[1][q] * r1 + Ll[2][q] * r2 + Ll[3][q] * r3;
  float invL = 1.0f / L;
  float rw[4] = { r0, r1, r2, r3 };
  float s[8] = {};
#pragma unroll
  for (int ww = 0; ww < 4; ++ww) {
    uint4 pr = *reinterpret_cast<const uint4*>(&Lo[ww][q][dg * 8]);
    unsigned int pu[4] = { pr.x, pr.y, pr.z, pr.w };
#pragma unroll
    for (int c = 0; c < 4; ++c) {
      s[c * 2]     += b2f((u16)(pu[c] & 0xffff)) * rw[ww];
      s[c * 2 + 1] += b2f((u16)(pu[c] >> 16)) * rw[ww];
    }
  }
  const int row = qr0 + q;
  const u16* gp = qg + (size_t)row * 4096 + h * 256 + 128 + dg * 8;
  uint4 gw = *reinterpret_cast<const uint4*>(gp);
  u16 gu[8] = { (u16)(gw.x & 0xffff), (u16)(gw.x >> 16), (u16)(gw.y & 0xffff), (u16)(gw.y >> 16),
                (u16)(gw.z & 0xffff), (u16)(gw.z >> 16), (u16)(gw.w & 0xffff), (u16)(gw.w >> 16) };
  u16 ou[8];
#pragma unroll
  for (int j = 0; j < 8; ++j) {
    float gate = b2f(gu[j]);
    float sig = 1.0f / (1.0f + __expf(-gate));
    ou[j] = f2b(s[j] * invL * sig);
  }
  *reinterpret_cast<uint4*>(outg + (size_t)row * 2048 + h * 128 + dg * 8) =
      *reinterpret_cast<uint4*>(ou);
}

extern "C" void kernel_launch(void* const* d_in, const int* in_sizes, int n_in,
                              void* d_out, int out_size, void* d_ws, size_t ws_size,
                              hipStream_t stream) {
  const float* x    = (const float*)d_in[0];
  const float* cosb = (const float*)d_in[1];
  const float* sinb = (const float*)d_in[2];
  const float* Wq   = (const float*)d_in[3];
  const float* Wk   = (const float*)d_in[4];
  const float* Wv   = (const float*)d_in[5];
  const float* Wo   = (const float*)d_in[6];
  const float* qnw  = (const float*)d_in[7];
  const float* knw  = (const float*)d_in[8];
  const int*   cu   = (const int*)d_in[9];
  const int n_seq = in_sizes[9] - 1;

  const int hidden = 2048, H = 16, KVH = 4, D = 128;
  const int total = in_sizes[0] / hidden;  // 4096
  const int NQ = H * D * 2;                // 4096
  const int NKV = KVH * D;                 // 512

  char* ws = (char*)d_ws;
  size_t off = 0;
  auto alloc = [&](size_t elems) {
    u16* p = (u16*)(ws + off);
    off += elems * 2;
    off = (off + 255) & ~(size_t)255;
    return p;
  };
  u16* xb   = alloc((size_t)total * hidden);
  u16* Wqb  = alloc((size_t)NQ * hidden);
  u16* Wkb  = alloc((size_t)NKV * hidden);
  u16* Wvb  = alloc((size_t)NKV * hidden);
  u16* Wob  = alloc((size_t)hidden * (H * D));
  u16* qgb  = alloc((size_t)total * NQ);
  u16* kbuf = alloc((size_t)total * NKV);
  u16* vbuf = alloc((size_t)total * NKV);
  u16* vtb  = alloc((size_t)total * NKV);
  u16* attg = Wqb;  // alias: Wqb dead after GEMM1

  auto cgrid = [](int n) { int g = (n / 4 + 255) / 256; return g > 2048 ? 2048 : g; };
  k_f2b<<<cgrid(total * hidden), 256, 0, stream>>>(x, xb, total * hidden);
  k_f2b<<<cgrid(NQ * hidden), 256, 0, stream>>>(Wq, Wqb, NQ * hidden);
  k_f2b<<<cgrid(NKV * hidden), 256, 0, stream>>>(Wk, Wkb, NKV * hidden);
  k_f2b<<<cgrid(NKV * hidden), 256, 0, stream>>>(Wv, Wvb, NKV * hidden);
  k_f2b<<<cgrid(hidden * H * D), 256, 0, stream>>>(Wo, Wob, hidden * H * D);

  k_gemm_bf16<<<dim3(NQ / 128, total / 128), 256, 0, stream>>>(xb, Wqb, qgb, total, NQ, hidden);
  k_gemm_kv<<<dim3(NKV / 128, total / 128, 2), 256, 0, stream>>>(xb, Wkb, Wvb, kbuf, vbuf,
                                                                 total, NKV, hidden);
  k_transpose<<<dim3(total / 32, NKV / 32), 256, 0, stream>>>(vbuf, vtb, total, NKV);
  const float qscale = 0.08838834764831845f * 1.4426950408889634f;  // 1/sqrt(D) * log2(e)
  k_normrope<<<total * H / 4, 256, 0, stream>>>(qgb, cosb, sinb, qnw, H, NQ, 2 * D, total, qscale);
  k_normrope<<<total * KVH / 4, 256, 0, stream>>>(kbuf, cosb, sinb, knw, KVH, NKV, D, total, 1.0f);
  k_attn<<<dim3(total / 16, H), 256, 0, stream>>>(qgb, kbuf, vtb, attg, cu, n_seq, total);
  k_gemm_f32<<<dim3(hidden / 128, total / 128), 256, 0, stream>>>(attg, Wob, (float*)d_out,
                                                                  total, hidden, H * D);
}